// Round 1
// baseline (542.775 us; speedup 1.0000x reference)
//
#include <hip/hip_runtime.h>
#include <hip/hip_bf16.h>
#include <cstdint>
#include <cstddef>

#define L_SEQ 1024
#define N_B   8
#define E_DIM 512
#define H_H   8
#define D_H   64
#define M_ROWS (L_SEQ * N_B)   // 8192
#define QKV_N (3 * E_DIM)      // 1536

// ---------------------------------------------------------------------------
// GEMM1: qkv = query @ W_in^T + b_in, with temporal scaling folded in:
//   q' = (q + bq) * 0.125 * exp(+t/1e6)   (row factor e_i)
//   k' = (k + bk) * exp(-t/1e6)           (col factor f_j)
//   v' =  v + bv
// scattered to [b][h][l][d] head-major layout.
// Tile 128x128, 256 threads, 8x8 per thread, BK=16, transposed LDS staging.
// ---------------------------------------------------------------------------
__global__ __launch_bounds__(256, 2) void inproj_kernel(
    const float* __restrict__ A, const float* __restrict__ W,
    const float* __restrict__ bias, const float* __restrict__ tptr,
    float* __restrict__ qh, float* __restrict__ kh, float* __restrict__ vh)
{
    __shared__ float Ast[16][132];   // stride 132 floats: 16B-aligned rows, no 4-way banks
    __shared__ float Bst[16][132];
    const int tid = threadIdx.x;
    const int m0 = blockIdx.x * 128;
    const int n0 = blockIdx.y * 128;
    const int ty = tid >> 4, tx = tid & 15;
    const int lr = tid >> 2;          // 0..63
    const int lc = (tid & 3) << 2;    // 0,4,8,12

    float acc[8][8];
    #pragma unroll
    for (int i = 0; i < 8; i++)
        #pragma unroll
        for (int j = 0; j < 8; j++) acc[i][j] = 0.f;

    for (int k0 = 0; k0 < E_DIM; k0 += 16) {
        __syncthreads();
        #pragma unroll
        for (int hh = 0; hh < 2; hh++) {
            const int row = lr + (hh << 6);
            const float4 av = *reinterpret_cast<const float4*>(
                &A[(size_t)(m0 + row) * E_DIM + k0 + lc]);
            Ast[lc + 0][row] = av.x; Ast[lc + 1][row] = av.y;
            Ast[lc + 2][row] = av.z; Ast[lc + 3][row] = av.w;
            const float4 bv = *reinterpret_cast<const float4*>(
                &W[(size_t)(n0 + row) * E_DIM + k0 + lc]);
            Bst[lc + 0][row] = bv.x; Bst[lc + 1][row] = bv.y;
            Bst[lc + 2][row] = bv.z; Bst[lc + 3][row] = bv.w;
        }
        __syncthreads();
        #pragma unroll
        for (int kk = 0; kk < 16; kk++) {
            const float4 a0 = *reinterpret_cast<const float4*>(&Ast[kk][8 * ty]);
            const float4 a1 = *reinterpret_cast<const float4*>(&Ast[kk][8 * ty + 4]);
            const float4 b0 = *reinterpret_cast<const float4*>(&Bst[kk][8 * tx]);
            const float4 b1 = *reinterpret_cast<const float4*>(&Bst[kk][8 * tx + 4]);
            const float av[8] = {a0.x, a0.y, a0.z, a0.w, a1.x, a1.y, a1.z, a1.w};
            const float bv[8] = {b0.x, b0.y, b0.z, b0.w, b1.x, b1.y, b1.z, b1.w};
            #pragma unroll
            for (int i = 0; i < 8; i++)
                #pragma unroll
                for (int j = 0; j < 8; j++)
                    acc[i][j] = fmaf(av[i], bv[j], acc[i][j]);
        }
    }

    // Epilogue: bias + temporal scaling + scatter
    const int nbase = n0 + 8 * tx;            // 8 consecutive output cols
    float bs[8];
    {
        const float4 c0 = *reinterpret_cast<const float4*>(&bias[nbase]);
        const float4 c1 = *reinterpret_cast<const float4*>(&bias[nbase + 4]);
        bs[0] = c0.x; bs[1] = c0.y; bs[2] = c0.z; bs[3] = c0.w;
        bs[4] = c1.x; bs[5] = c1.y; bs[6] = c1.z; bs[7] = c1.w;
    }
    const int sec    = nbase >> 9;     // 0:q 1:k 2:v (128-col tile never straddles)
    const int within = nbase & 511;
    const int hh     = within >> 6;    // head
    const int dd     = within & 63;    // d offset (multiple of 8)
    float* dst = (sec == 0) ? qh : (sec == 1) ? kh : vh;

    #pragma unroll
    for (int i = 0; i < 8; i++) {
        const int m = m0 + 8 * ty + i;
        const int l = m >> 3, b = m & 7;
        float scale = 1.f;
        if (sec == 0)      scale = 0.125f * __expf(tptr[m] *  1e-6f);
        else if (sec == 1) scale =          __expf(tptr[m] * -1e-6f);
        float v[8];
        #pragma unroll
        for (int j = 0; j < 8; j++) v[j] = (acc[i][j] + bs[j]) * scale;
        float* p = &dst[(((size_t)(b * H_H + hh)) * L_SEQ + l) * D_H + dd];
        *reinterpret_cast<float4*>(p)     = make_float4(v[0], v[1], v[2], v[3]);
        *reinterpret_cast<float4*>(p + 4) = make_float4(v[4], v[5], v[6], v[7]);
    }
}

// ---------------------------------------------------------------------------
// Flash attention, fp32. One block = one (b,h) x 64-row q-tile.
// 256 threads as 16x16; each thread owns 4x4 of S/P and 4x4 of O.
// Online softmax per row with 16-lane shfl_xor reductions.
// ---------------------------------------------------------------------------
__global__ __launch_bounds__(256, 2) void attn_kernel(
    const float* __restrict__ qh, const float* __restrict__ kh,
    const float* __restrict__ vh, float* __restrict__ ao)
{
    __shared__ float Qt[64][68];   // [d][r] transposed; stride 68 => 16B-aligned rows
    __shared__ float Kt[64][68];   // [d][c] transposed
    __shared__ float Vs[64][68];   // [c][d] row-major
    __shared__ float Pt[64][68];   // [c][r] transposed P

    const int bh = blockIdx.x;     // b*H + h
    const int qt = blockIdx.y;     // q tile
    const int b = bh >> 3, h = bh & 7;
    const int tid = threadIdx.x;
    const int ty = tid >> 4, tx = tid & 15;

    const float* qbase = qh + ((size_t)bh * L_SEQ + qt * 64) * D_H;
    const float* kbase = kh + (size_t)bh * L_SEQ * D_H;
    const float* vbase = vh + (size_t)bh * L_SEQ * D_H;

    {   // stage Q transposed (once)
        const int r  = tid >> 2;
        const int dc = (tid & 3) << 4;
        #pragma unroll
        for (int u = 0; u < 4; u++) {
            const float4 qv = *reinterpret_cast<const float4*>(&qbase[(size_t)r * D_H + dc + 4 * u]);
            Qt[dc + 4 * u + 0][r] = qv.x; Qt[dc + 4 * u + 1][r] = qv.y;
            Qt[dc + 4 * u + 2][r] = qv.z; Qt[dc + 4 * u + 3][r] = qv.w;
        }
    }

    float o[4][4], m_run[4], l_run[4];
    #pragma unroll
    for (int i = 0; i < 4; i++) {
        m_run[i] = -1e30f; l_run[i] = 0.f;
        #pragma unroll
        for (int j = 0; j < 4; j++) o[i][j] = 0.f;
    }

    for (int kt = 0; kt < 16; kt++) {
        __syncthreads();   // previous iter's Kt/Vs/Pt reads complete
        {   // stage K chunk transposed + V chunk direct
            const int r  = tid >> 2;
            const int dc = (tid & 3) << 4;
            const size_t gro = (size_t)(kt * 64 + r) * D_H + dc;
            #pragma unroll
            for (int u = 0; u < 4; u++) {
                const float4 kv = *reinterpret_cast<const float4*>(&kbase[gro + 4 * u]);
                Kt[dc + 4 * u + 0][r] = kv.x; Kt[dc + 4 * u + 1][r] = kv.y;
                Kt[dc + 4 * u + 2][r] = kv.z; Kt[dc + 4 * u + 3][r] = kv.w;
                const float4 vv = *reinterpret_cast<const float4*>(&vbase[gro + 4 * u]);
                *reinterpret_cast<float4*>(&Vs[r][dc + 4 * u]) = vv;
            }
        }
        __syncthreads();

        // S = Q @ K^T (64x64 chunk)
        float s[4][4];
        #pragma unroll
        for (int i = 0; i < 4; i++)
            #pragma unroll
            for (int j = 0; j < 4; j++) s[i][j] = 0.f;
        #pragma unroll 4
        for (int d = 0; d < 64; d++) {
            const float4 qv = *reinterpret_cast<const float4*>(&Qt[d][4 * ty]);
            const float4 kv = *reinterpret_cast<const float4*>(&Kt[d][4 * tx]);
            const float qa[4] = {qv.x, qv.y, qv.z, qv.w};
            const float ka[4] = {kv.x, kv.y, kv.z, kv.w};
            #pragma unroll
            for (int i = 0; i < 4; i++)
                #pragma unroll
                for (int j = 0; j < 4; j++)
                    s[i][j] = fmaf(qa[i], ka[j], s[i][j]);
        }

        // online softmax (per-row stats replicated across the 16 tx lanes)
        #pragma unroll
        for (int i = 0; i < 4; i++) {
            float mx = fmaxf(fmaxf(s[i][0], s[i][1]), fmaxf(s[i][2], s[i][3]));
            mx = fmaxf(mx, __shfl_xor(mx, 1));
            mx = fmaxf(mx, __shfl_xor(mx, 2));
            mx = fmaxf(mx, __shfl_xor(mx, 4));
            mx = fmaxf(mx, __shfl_xor(mx, 8));
            const float mn = fmaxf(m_run[i], mx);
            const float f  = __expf(m_run[i] - mn);
            float sum = 0.f;
            #pragma unroll
            for (int j = 0; j < 4; j++) { s[i][j] = __expf(s[i][j] - mn); sum += s[i][j]; }
            sum += __shfl_xor(sum, 1);
            sum += __shfl_xor(sum, 2);
            sum += __shfl_xor(sum, 4);
            sum += __shfl_xor(sum, 8);
            l_run[i] = l_run[i] * f + sum;
            m_run[i] = mn;
            #pragma unroll
            for (int j = 0; j < 4; j++) o[i][j] *= f;
        }

        // stage P transposed (Pt last read before loop-top barrier -> safe)
        #pragma unroll
        for (int i = 0; i < 4; i++)
            #pragma unroll
            for (int j = 0; j < 4; j++)
                Pt[4 * tx + j][4 * ty + i] = s[i][j];
        __syncthreads();

        // O += P @ V
        #pragma unroll 4
        for (int c = 0; c < 64; c++) {
            const float4 pv = *reinterpret_cast<const float4*>(&Pt[c][4 * ty]);
            const float4 vv = *reinterpret_cast<const float4*>(&Vs[c][4 * tx]);
            const float pa[4] = {pv.x, pv.y, pv.z, pv.w};
            const float va[4] = {vv.x, vv.y, vv.z, vv.w};
            #pragma unroll
            for (int i = 0; i < 4; i++)
                #pragma unroll
                for (int j = 0; j < 4; j++)
                    o[i][j] = fmaf(pa[i], va[j], o[i][j]);
        }
    }

    // normalize + store to (L, N, E) layout
    #pragma unroll
    for (int i = 0; i < 4; i++) {
        const float inv = 1.f / l_run[i];
        const int lrow = qt * 64 + 4 * ty + i;
        const float4 ov = make_float4(o[i][0] * inv, o[i][1] * inv,
                                      o[i][2] * inv, o[i][3] * inv);
        *reinterpret_cast<float4*>(
            &ao[((size_t)lrow * N_B + b) * E_DIM + h * D_H + 4 * tx]) = ov;
    }
}

// ---------------------------------------------------------------------------
// GEMM2: out = ao @ W_out^T + b_out   (8192x512)@(512x512)
// ---------------------------------------------------------------------------
__global__ __launch_bounds__(256, 2) void outproj_kernel(
    const float* __restrict__ A, const float* __restrict__ W,
    const float* __restrict__ bias, float* __restrict__ out)
{
    __shared__ float Ast[16][132];
    __shared__ float Bst[16][132];
    const int tid = threadIdx.x;
    const int m0 = blockIdx.x * 128;
    const int n0 = blockIdx.y * 128;
    const int ty = tid >> 4, tx = tid & 15;
    const int lr = tid >> 2;
    const int lc = (tid & 3) << 2;

    float acc[8][8];
    #pragma unroll
    for (int i = 0; i < 8; i++)
        #pragma unroll
        for (int j = 0; j < 8; j++) acc[i][j] = 0.f;

    for (int k0 = 0; k0 < E_DIM; k0 += 16) {
        __syncthreads();
        #pragma unroll
        for (int hh = 0; hh < 2; hh++) {
            const int row = lr + (hh << 6);
            const float4 av = *reinterpret_cast<const float4*>(
                &A[(size_t)(m0 + row) * E_DIM + k0 + lc]);
            Ast[lc + 0][row] = av.x; Ast[lc + 1][row] = av.y;
            Ast[lc + 2][row] = av.z; Ast[lc + 3][row] = av.w;
            const float4 bv = *reinterpret_cast<const float4*>(
                &W[(size_t)(n0 + row) * E_DIM + k0 + lc]);
            Bst[lc + 0][row] = bv.x; Bst[lc + 1][row] = bv.y;
            Bst[lc + 2][row] = bv.z; Bst[lc + 3][row] = bv.w;
        }
        __syncthreads();
        #pragma unroll
        for (int kk = 0; kk < 16; kk++) {
            const float4 a0 = *reinterpret_cast<const float4*>(&Ast[kk][8 * ty]);
            const float4 a1 = *reinterpret_cast<const float4*>(&Ast[kk][8 * ty + 4]);
            const float4 b0 = *reinterpret_cast<const float4*>(&Bst[kk][8 * tx]);
            const float4 b1 = *reinterpret_cast<const float4*>(&Bst[kk][8 * tx + 4]);
            const float av[8] = {a0.x, a0.y, a0.z, a0.w, a1.x, a1.y, a1.z, a1.w};
            const float bv[8] = {b0.x, b0.y, b0.z, b0.w, b1.x, b1.y, b1.z, b1.w};
            #pragma unroll
            for (int i = 0; i < 8; i++)
                #pragma unroll
                for (int j = 0; j < 8; j++)
                    acc[i][j] = fmaf(av[i], bv[j], acc[i][j]);
        }
    }

    const int nbase = n0 + 8 * tx;
    float bs[8];
    {
        const float4 c0 = *reinterpret_cast<const float4*>(&bias[nbase]);
        const float4 c1 = *reinterpret_cast<const float4*>(&bias[nbase + 4]);
        bs[0] = c0.x; bs[1] = c0.y; bs[2] = c0.z; bs[3] = c0.w;
        bs[4] = c1.x; bs[5] = c1.y; bs[6] = c1.z; bs[7] = c1.w;
    }
    #pragma unroll
    for (int i = 0; i < 8; i++) {
        const int m = m0 + 8 * ty + i;
        float v[8];
        #pragma unroll
        for (int j = 0; j < 8; j++) v[j] = acc[i][j] + bs[j];
        float* p = &out[(size_t)m * E_DIM + nbase];
        *reinterpret_cast<float4*>(p)     = make_float4(v[0], v[1], v[2], v[3]);
        *reinterpret_cast<float4*>(p + 4) = make_float4(v[4], v[5], v[6], v[7]);
    }
}

// ---------------------------------------------------------------------------
extern "C" void kernel_launch(void* const* d_in, const int* in_sizes, int n_in,
                              void* d_out, int out_size, void* d_ws, size_t ws_size,
                              hipStream_t stream) {
    const float* query = (const float*)d_in[0];   // (L, N, E)
    const float* timep = (const float*)d_in[1];   // (L, N, 1)
    const float* w_in  = (const float*)d_in[2];   // (3E, E)
    const float* b_in  = (const float*)d_in[3];   // (3E,)
    const float* w_out = (const float*)d_in[4];   // (E, E)
    const float* b_out = (const float*)d_in[5];   // (E,)
    float* out = (float*)d_out;                   // (L, N, E)

    // workspace: qh | kh | vh | ao, each L*N*E floats (16.78 MB) = 67 MB total
    float* ws = (float*)d_ws;
    const size_t SZ = (size_t)L_SEQ * N_B * E_DIM;
    float* qh = ws;
    float* kh = ws + SZ;
    float* vh = ws + 2 * SZ;
    float* ao = ws + 3 * SZ;

    const dim3 blk(256);
    inproj_kernel<<<dim3(M_ROWS / 128, QKV_N / 128), blk, 0, stream>>>(
        query, w_in, b_in, timep, qh, kh, vh);
    attn_kernel<<<dim3(N_B * H_H, L_SEQ / 64), blk, 0, stream>>>(qh, kh, vh, ao);
    outproj_kernel<<<dim3(M_ROWS / 128, E_DIM / 128), blk, 0, stream>>>(
        ao, w_out, b_out, out);
}

// Round 3
// 143.519 us; speedup vs baseline: 3.7819x; 3.7819x over previous
//
#include <hip/hip_runtime.h>
#include <cstdint>
#include <cstddef>

typedef unsigned short u16;
typedef unsigned int u32;
typedef __attribute__((ext_vector_type(8))) short short8;   // 8 x bf16 (4 VGPR)
typedef __attribute__((ext_vector_type(4))) float f32x4;
typedef __attribute__((ext_vector_type(16))) float f32x16;

#define L_SEQ 1024
#define N_B   8
#define E_DIM 512
#define H_H   8
#define D_H   64
#define M_ROWS 8192

// round-to-nearest-even fp32 -> bf16
__device__ __forceinline__ u16 f2bf(float f) {
    u32 u = __float_as_uint(f);
    u32 r = (u + 0x7fffu + ((u >> 16) & 1u)) >> 16;
    return (u16)r;
}

// async global->LDS, 16B per lane; lds base must be wave-uniform (HW adds lane*16)
__device__ __forceinline__ void gload16(const void* g, void* l) {
    __builtin_amdgcn_global_load_lds(
        (__attribute__((address_space(1))) void*)(g),
        (__attribute__((address_space(3))) void*)(l), 16, 0, 0);
}

// swizzled LDS tile read: tile rows are 128 B (64 bf16); 16B chunk c stored at c^(row&7)
__device__ __forceinline__ short8 ldsw(const u16* base, int row, int c) {
    return *reinterpret_cast<const short8*>(
        reinterpret_cast<const char*>(base) + row * 128 + ((c ^ (row & 7)) << 4));
}

// ---------------------------------------------------------------------------
// fp32 -> bf16 conversion prepass for query, w_in, w_out
// ---------------------------------------------------------------------------
__global__ __launch_bounds__(256) void convert_kernel(
    const float* __restrict__ a, const float* __restrict__ b, const float* __restrict__ c,
    u16* __restrict__ ab, u16* __restrict__ bb, u16* __restrict__ cb)
{
    const int NA = M_ROWS * E_DIM / 4;       // 1048576
    const int NB = 1536 * E_DIM / 4;         // 196608
    const int i4 = blockIdx.x * 256 + threadIdx.x;
    const float* src; u16* dst; int j;
    if (i4 < NA)           { src = a; dst = ab; j = i4; }
    else if (i4 < NA + NB) { src = b; dst = bb; j = i4 - NA; }
    else                   { src = c; dst = cb; j = i4 - NA - NB; }
    const float4 v = reinterpret_cast<const float4*>(src)[j];
    ushort4 o;
    o.x = f2bf(v.x); o.y = f2bf(v.y); o.z = f2bf(v.z); o.w = f2bf(v.w);
    reinterpret_cast<ushort4*>(dst)[j] = o;
}

// ---------------------------------------------------------------------------
// bf16 MFMA GEMM: C[m][n] = sum_k A[m][k]*W[n][k]  (A row-major MxK, W NxK)
// 128x128 tile, 4 waves (2x2), BK=64, global_load_lds + XOR-swizzled LDS.
// MODE 0: inproj epilogue (bias + temporal scaling, scatter bf16 q/k/v head-major)
// MODE 1: outproj epilogue (bias, fp32 out)
// ---------------------------------------------------------------------------
template <int MODE>
__global__ __launch_bounds__(256, 2) void gemm_kernel(
    const u16* __restrict__ A, const u16* __restrict__ B,
    const float* __restrict__ bias, const float* __restrict__ tptr,
    u16* __restrict__ qh, u16* __restrict__ kh, u16* __restrict__ vh,
    float* __restrict__ outf)
{
    __shared__ __align__(16) u16 Asm[128 * 64];
    __shared__ __align__(16) u16 Bsm[128 * 64];
    const int tid = threadIdx.x;
    const int lane = tid & 63, w = tid >> 6;
    const int wm = w >> 1, wn = w & 1;
    const int m0 = blockIdx.x * 128, n0 = blockIdx.y * 128;

    f32x4 acc[4][4];
    #pragma unroll
    for (int mi = 0; mi < 4; ++mi)
        #pragma unroll
        for (int ni = 0; ni < 4; ++ni)
            #pragma unroll
            for (int r = 0; r < 4; ++r) acc[mi][ni][r] = 0.f;

    const int srow = (w << 3) + (lane >> 3);                 // staging row (mod 32-block)
    const int csrc = ((lane & 7) ^ (lane >> 3)) << 3;        // pre-swizzled source chunk

    for (int kt = 0; kt < 8; ++kt) {
        __syncthreads();
        #pragma unroll
        for (int i = 0; i < 4; ++i) {
            const int row = (i << 5) + srow;                 // 0..127
            gload16(A + (size_t)(m0 + row) * 512 + (kt << 6) + csrc,
                    (char*)Asm + (i << 12) + (w << 10));
            gload16(B + (size_t)(n0 + row) * 512 + (kt << 6) + csrc,
                    (char*)Bsm + (i << 12) + (w << 10));
        }
        __syncthreads();
        #pragma unroll
        for (int k01 = 0; k01 < 2; ++k01) {
            short8 af[4], bfr[4];
            #pragma unroll
            for (int x = 0; x < 4; ++x) {
                af[x]  = ldsw(Asm, (wm << 6) + (x << 4) + (lane & 15), (k01 << 2) + (lane >> 4));
                bfr[x] = ldsw(Bsm, (wn << 6) + (x << 4) + (lane & 15), (k01 << 2) + (lane >> 4));
            }
            #pragma unroll
            for (int mi = 0; mi < 4; ++mi)
                #pragma unroll
                for (int ni = 0; ni < 4; ++ni)
                    acc[mi][ni] = __builtin_amdgcn_mfma_f32_16x16x32_bf16(
                        af[mi], bfr[ni], acc[mi][ni], 0, 0, 0);
        }
    }

    // epilogue
    const int nb = n0 + (wn << 6) + (lane & 15);
    const int mb = m0 + (wm << 6) + ((lane >> 4) << 2);
    float bsv[4];
    #pragma unroll
    for (int ni = 0; ni < 4; ++ni) bsv[ni] = bias[nb + (ni << 4)];
    const int sec = n0 >> 9;   // 0:q 1:k 2:v (uniform per block)

    #pragma unroll
    for (int mi = 0; mi < 4; ++mi) {
        #pragma unroll
        for (int r = 0; r < 4; ++r) {
            const int m = mb + (mi << 4) + r;
            float scale = 1.f;
            if (MODE == 0) {
                if (sec == 0)      scale = 0.125f * __expf(tptr[m] * 1e-6f);
                else if (sec == 1) scale = __expf(tptr[m] * -1e-6f);
            }
            #pragma unroll
            for (int ni = 0; ni < 4; ++ni) {
                const int n = nb + (ni << 4);
                const float v = acc[mi][ni][r] + bsv[ni];
                if (MODE == 0) {
                    const int l_seq = m >> 3, bb2 = m & 7;
                    const int hh = (n & 511) >> 6, dd = n & 63;
                    u16* dst = (sec == 0) ? qh : (sec == 1) ? kh : vh;
                    dst[(((size_t)(bb2 << 3) + hh) * L_SEQ + l_seq) * D_H + dd] = f2bf(v * scale);
                } else {
                    outf[(size_t)m * 512 + n] = v;
                }
            }
        }
    }
}

// ---------------------------------------------------------------------------
// V transpose: vh [bh][kv][d] bf16 -> vt [bh][d][kv] bf16 (64x64 tiles via LDS)
// write-side 16B chunks XOR-swizzled by (row&7)^((row>>3)&7) for conflict-free
// column reads.
// ---------------------------------------------------------------------------
__global__ __launch_bounds__(256) void transpose_v(
    const u16* __restrict__ vh, u16* __restrict__ vt)
{
    __shared__ __align__(16) u16 T[64 * 64];
    const int bh = blockIdx.x, kt = blockIdx.y;
    const u16* src = vh + ((size_t)bh * L_SEQ + kt * 64) * D_H;

    #pragma unroll
    for (int rnd = 0; rnd < 2; ++rnd) {
        const int slot = rnd * 256 + threadIdx.x;   // 0..511
        const int row = slot >> 3, c = slot & 7;    // row = kv, c = 16B d-chunk
        const uint4 v = *reinterpret_cast<const uint4*>(src + row * 64 + c * 8);
        const int cs = c ^ (row & 7) ^ ((row >> 3) & 7);
        *reinterpret_cast<uint4*>(&T[row * 64 + cs * 8]) = v;
    }
    __syncthreads();
    #pragma unroll
    for (int rnd = 0; rnd < 2; ++rnd) {
        const int slot = rnd * 256 + threadIdx.x;
        const int d = slot >> 3, kc = slot & 7;
        u16 tmp[8];
        #pragma unroll
        for (int j = 0; j < 8; ++j) {
            const int row = kc * 8 + j;
            const int col = (((d >> 3) ^ (row & 7) ^ ((row >> 3) & 7)) << 3) + (d & 7);
            tmp[j] = T[row * 64 + col];
        }
        *reinterpret_cast<uint4*>(vt + ((size_t)bh * D_H + d) * L_SEQ + kt * 64 + kc * 8) =
            *reinterpret_cast<uint4*>(tmp);
    }
}

// ---------------------------------------------------------------------------
// Flash attention, bf16 MFMA 32x32x16, swapped QK^T (S^T in regs), online
// softmax lane-local, PV as O^T = V^T @ P^T. 4 waves x 32 q-rows = 128 q/block.
// ---------------------------------------------------------------------------
__global__ __launch_bounds__(256, 2) void attn_kernel(
    const u16* __restrict__ qh, const u16* __restrict__ kh,
    const u16* __restrict__ vt, u16* __restrict__ ao)
{
    __shared__ __align__(16) float SMEMf[8448];   // 33 KB; [0,16KB) K/V staging; all: O xpose
    u16* Ksm = reinterpret_cast<u16*>(SMEMf);     // 64x64 bf16, swizzled rows
    u16* Vsm = Ksm + 4096;                        // 64x64 bf16 (V^T chunk)

    const int tid = threadIdx.x;
    const int lane = tid & 63, w = tid >> 6;
    const int hi = lane >> 5, q31 = lane & 31;
    const int bh = blockIdx.x, qt = blockIdx.y;
    const int b = bh >> 3, h = bh & 7;

    // Q fragments (B-operand of S^T = K @ Q^T): lane: q=q31, d = 16ks+8hi+j
    const u16* qrow = qh + ((size_t)bh * L_SEQ + qt * 128 + w * 32 + q31) * D_H;
    short8 qf[4];
    #pragma unroll
    for (int ks = 0; ks < 4; ++ks)
        qf[ks] = *reinterpret_cast<const short8*>(qrow + ks * 16 + hi * 8);

    f32x16 oacc[2];
    #pragma unroll
    for (int d = 0; d < 2; ++d)
        #pragma unroll
        for (int r = 0; r < 16; ++r) oacc[d][r] = 0.f;
    float m_run = -1e30f, l_run = 0.f;

    const u16* kbase = kh + (size_t)bh * L_SEQ * D_H;
    const u16* vbase = vt + (size_t)bh * D_H * L_SEQ;
    const int srow = (w << 3) + (lane >> 3);
    const int csrc = ((lane & 7) ^ (lane >> 3)) << 3;

    for (int kt = 0; kt < 16; ++kt) {
        __syncthreads();
        #pragma unroll
        for (int i = 0; i < 2; ++i) {
            const int row = i * 32 + srow;          // K: kv row / V^T: d row
            gload16(kbase + (size_t)(kt * 64 + row) * 64 + csrc,
                    (char*)Ksm + (i << 12) + (w << 10));
            gload16(vbase + (size_t)row * L_SEQ + kt * 64 + csrc,
                    (char*)Vsm + (i << 12) + (w << 10));
        }
        __syncthreads();

        // S^T[kv][q] in 2 kv-blocks of 32
        f32x16 s[2];
        #pragma unroll
        for (int d = 0; d < 2; ++d)
            #pragma unroll
            for (int r = 0; r < 16; ++r) s[d][r] = 0.f;
        #pragma unroll
        for (int ks = 0; ks < 4; ++ks) {
            const int c = 2 * ks + hi;
            const short8 ka0 = ldsw(Ksm, q31, c);
            const short8 ka1 = ldsw(Ksm, 32 + q31, c);
            s[0] = __builtin_amdgcn_mfma_f32_32x32x16_bf16(ka0, qf[ks], s[0], 0, 0, 0);
            s[1] = __builtin_amdgcn_mfma_f32_32x32x16_bf16(ka1, qf[ks], s[1], 0, 0, 0);
        }

        // online softmax: lane holds 32 of 64 kv values for q=q31; partner lane^32 rest
        float mx = -1e30f;
        #pragma unroll
        for (int hh = 0; hh < 2; ++hh)
            #pragma unroll
            for (int r = 0; r < 16; ++r) mx = fmaxf(mx, s[hh][r]);
        mx = fmaxf(mx, __shfl_xor(mx, 32));
        const float mn = fmaxf(m_run, mx);
        const float fr = __expf(m_run - mn);
        float p[2][16];
        float sum = 0.f;
        #pragma unroll
        for (int hh = 0; hh < 2; ++hh)
            #pragma unroll
            for (int r = 0; r < 16; ++r) {
                const float e = __expf(s[hh][r] - mn);
                p[hh][r] = e; sum += e;
            }
        sum += __shfl_xor(sum, 32);
        l_run = l_run * fr + sum;
        m_run = mn;
        #pragma unroll
        for (int d = 0; d < 2; ++d) oacc[d] *= fr;

        // P -> bf16 b_frags (pack own quads, exchange partner half) + PV MFMAs
        #pragma unroll
        for (int ks = 0; ks < 4; ++ks) {
            const int e = ks & 1, hh = ks >> 1;
            const u32 pkA = (u32)f2bf(p[hh][8 * e + 0]) | ((u32)f2bf(p[hh][8 * e + 1]) << 16);
            const u32 pkB = (u32)f2bf(p[hh][8 * e + 2]) | ((u32)f2bf(p[hh][8 * e + 3]) << 16);
            const u32 pkC = (u32)f2bf(p[hh][8 * e + 4]) | ((u32)f2bf(p[hh][8 * e + 5]) << 16);
            const u32 pkD = (u32)f2bf(p[hh][8 * e + 6]) | ((u32)f2bf(p[hh][8 * e + 7]) << 16);
            const u32 keep0 = hi ? pkC : pkA, keep1 = hi ? pkD : pkB;
            const u32 send0 = hi ? pkA : pkC, send1 = hi ? pkB : pkD;
            const u32 r0 = (u32)__shfl_xor((int)send0, 32);
            const u32 r1 = (u32)__shfl_xor((int)send1, 32);
            union { u32 u[4]; short8 v; } pf;
            pf.u[0] = hi ? r0 : keep0;  pf.u[1] = hi ? r1 : keep1;
            pf.u[2] = hi ? keep0 : r0;  pf.u[3] = hi ? keep1 : r1;
            const int c = 2 * ks + hi;
            const short8 va0 = ldsw(Vsm, q31, c);       // V^T rows = d
            const short8 va1 = ldsw(Vsm, 32 + q31, c);
            oacc[0] = __builtin_amdgcn_mfma_f32_32x32x16_bf16(va0, pf.v, oacc[0], 0, 0, 0);
            oacc[1] = __builtin_amdgcn_mfma_f32_32x32x16_bf16(va1, pf.v, oacc[1], 0, 0, 0);
        }
    }

    // epilogue: O^T regs -> LDS -> coalesced bf16 store (L,N,E layout)
    __syncthreads();            // everyone done with Ksm/Vsm (overlaps O region)
    const float inv = 1.f / l_run;
    float* myO = SMEMf + w * 2080;          // [32 q][65 d-padded]
    #pragma unroll
    for (int dh = 0; dh < 2; ++dh)
        #pragma unroll
        for (int r = 0; r < 16; ++r) {
            const int d = dh * 32 + (r & 3) + 8 * (r >> 2) + 4 * hi;
            myO[q31 * 65 + d] = oacc[dh][r] * inv;
        }
    __syncthreads();            // make cross-lane LDS writes visible before readback
    #pragma unroll
    for (int i = 0; i < 4; ++i) {
        const int slot = i * 64 + lane;
        const int qq = slot >> 3, dc = slot & 7;
        u16 outv[8];
        #pragma unroll
        for (int j = 0; j < 8; ++j) outv[j] = f2bf(myO[qq * 65 + dc * 8 + j]);
        const int lrow = qt * 128 + w * 32 + qq;
        *reinterpret_cast<uint4*>(ao + ((size_t)lrow * N_B + b) * E_DIM + h * 64 + dc * 8) =
            *reinterpret_cast<uint4*>(outv);
    }
}

// ---------------------------------------------------------------------------
extern "C" void kernel_launch(void* const* d_in, const int* in_sizes, int n_in,
                              void* d_out, int out_size, void* d_ws, size_t ws_size,
                              hipStream_t stream) {
    const float* query = (const float*)d_in[0];
    const float* timep = (const float*)d_in[1];
    const float* w_in  = (const float*)d_in[2];
    const float* b_in  = (const float*)d_in[3];
    const float* w_out = (const float*)d_in[4];
    const float* b_out = (const float*)d_in[5];
    float* out = (float*)d_out;

    u16* ws = (u16*)d_ws;
    const size_t SZ = (size_t)M_ROWS * E_DIM;        // 4194304 elems
    u16* Abf  = ws;                    // query bf16       [8192][512]
    u16* Wibf = Abf + SZ;              // w_in bf16        [1536][512]
    u16* Wobf = Wibf + 1536 * 512;     // w_out bf16       [512][512]
    u16* qhb  = Wobf + 512 * 512;      // q' head-major    [64][1024][64]
    u16* khb  = qhb + SZ;              // k'
    u16* vhb  = khb + SZ;              // v
    u16* vtb  = vhb + SZ;              // v^T              [64][64][1024]
    u16* aob  = vtb + SZ;              // attn out bf16    [8192][512]

    convert_kernel<<<5120, 256, 0, stream>>>(query, w_in, w_out, Abf, Wibf, Wobf);
    gemm_kernel<0><<<dim3(64, 12), 256, 0, stream>>>(
        Abf, Wibf, b_in, timep, qhb, khb, vhb, nullptr);
    transpose_v<<<dim3(64, 16), 256, 0, stream>>>(vhb, vtb);
    attn_kernel<<<dim3(64, 8), 256, 0, stream>>>(qhb, khb, vtb, aob);
    gemm_kernel<1><<<dim3(64, 4), 256, 0, stream>>>(
        aob, Wobf, b_out, nullptr, nullptr, nullptr, nullptr, out);
}

// Round 4
// 142.673 us; speedup vs baseline: 3.8043x; 1.0059x over previous
//
#include <hip/hip_runtime.h>
#include <cstdint>
#include <cstddef>

typedef unsigned short u16;
typedef unsigned int u32;
typedef __attribute__((ext_vector_type(8))) short short8;   // 8 x bf16 (4 VGPR)
typedef __attribute__((ext_vector_type(4))) float f32x4;
typedef __attribute__((ext_vector_type(16))) float f32x16;

#define L_SEQ 1024
#define N_B   8
#define E_DIM 512
#define H_H   8
#define D_H   64
#define M_ROWS 8192

#if __has_builtin(__builtin_amdgcn_exp2f)
#define EXP2(x) __builtin_amdgcn_exp2f(x)
#else
#define EXP2(x) exp2f(x)
#endif

// round-to-nearest-even fp32 -> bf16 (epilogue/convert paths)
__device__ __forceinline__ u16 f2bf(float f) {
    u32 u = __float_as_uint(f);
    u32 r = (u + 0x7fffu + ((u >> 16) & 1u)) >> 16;
    return (u16)r;
}

// packed fp32x2 -> bf16x2 (hot path): 1 instr instead of ~8
__device__ __forceinline__ u32 cvtpk(float lo, float hi_) {
    u32 r;
    asm("v_cvt_pk_bf16_f32 %0, %1, %2" : "=v"(r) : "v"(lo), "v"(hi_));
    return r;
}

// async global->LDS, 16B per lane; lds base must be wave-uniform (HW adds lane*16)
__device__ __forceinline__ void gload16(const void* g, void* l) {
    __builtin_amdgcn_global_load_lds(
        (__attribute__((address_space(1))) void*)(g),
        (__attribute__((address_space(3))) void*)(l), 16, 0, 0);
}

// swizzled LDS tile read: tile rows are 128 B (64 bf16); 16B chunk c stored at c^(row&7)
__device__ __forceinline__ short8 ldsw(const u16* base, int row, int c) {
    return *reinterpret_cast<const short8*>(
        reinterpret_cast<const char*>(base) + row * 128 + ((c ^ (row & 7)) << 4));
}

// ---------------------------------------------------------------------------
// fp32 -> bf16 conversion prepass for query, w_in, w_out
// ---------------------------------------------------------------------------
__global__ __launch_bounds__(256) void convert_kernel(
    const float* __restrict__ a, const float* __restrict__ b, const float* __restrict__ c,
    u16* __restrict__ ab, u16* __restrict__ bb, u16* __restrict__ cb)
{
    const int NA = M_ROWS * E_DIM / 4;       // 1048576
    const int NB = 1536 * E_DIM / 4;         // 196608
    const int i4 = blockIdx.x * 256 + threadIdx.x;
    const float* src; u16* dst; int j;
    if (i4 < NA)           { src = a; dst = ab; j = i4; }
    else if (i4 < NA + NB) { src = b; dst = bb; j = i4 - NA; }
    else                   { src = c; dst = cb; j = i4 - NA - NB; }
    const float4 v = reinterpret_cast<const float4*>(src)[j];
    ushort4 o;
    o.x = f2bf(v.x); o.y = f2bf(v.y); o.z = f2bf(v.z); o.w = f2bf(v.w);
    reinterpret_cast<ushort4*>(dst)[j] = o;
}

// ---------------------------------------------------------------------------
// bf16 MFMA GEMM: C[m][n] = sum_k A[m][k]*W[n][k]  (A row-major MxK, W NxK)
// Tile BM x 128 (BM = MI*32), 4 waves (2x2), BK=64, gload_lds + XOR swizzle.
// MODE 0: inproj epilogue (bias + temporal scaling [log2e folded into q],
//         scatter bf16 q/k/v head-major)
// MODE 1: outproj epilogue (bias, fp32 out)
// ---------------------------------------------------------------------------
template <int MODE, int MI>
__global__ __launch_bounds__(256, 2) void gemm_kernel(
    const u16* __restrict__ A, const u16* __restrict__ B,
    const float* __restrict__ bias, const float* __restrict__ tptr,
    u16* __restrict__ qh, u16* __restrict__ kh, u16* __restrict__ vh,
    float* __restrict__ outf)
{
    constexpr int BM = MI * 32;
    __shared__ __align__(16) u16 Asm_[BM * 64];
    __shared__ __align__(16) u16 Bsm[128 * 64];
    const int tid = threadIdx.x;
    const int lane = tid & 63, w = tid >> 6;
    const int wm = w >> 1, wn = w & 1;
    const int m0 = blockIdx.x * BM, n0 = blockIdx.y * 128;

    f32x4 acc[MI][4];
    #pragma unroll
    for (int mi = 0; mi < MI; ++mi)
        #pragma unroll
        for (int ni = 0; ni < 4; ++ni)
            #pragma unroll
            for (int r = 0; r < 4; ++r) acc[mi][ni][r] = 0.f;

    const int srow = (w << 3) + (lane >> 3);                 // 0..31
    const int csrc = ((lane & 7) ^ (lane >> 3)) << 3;        // pre-swizzled source chunk

    for (int kt = 0; kt < 8; ++kt) {
        __syncthreads();
        #pragma unroll
        for (int i = 0; i < MI; ++i) {
            const int row = (i << 5) + srow;
            gload16(A + (size_t)(m0 + row) * 512 + (kt << 6) + csrc,
                    (char*)Asm_ + (i << 12) + (w << 10));
        }
        #pragma unroll
        for (int i = 0; i < 4; ++i) {
            const int row = (i << 5) + srow;
            gload16(B + (size_t)(n0 + row) * 512 + (kt << 6) + csrc,
                    (char*)Bsm + (i << 12) + (w << 10));
        }
        __syncthreads();
        #pragma unroll
        for (int k01 = 0; k01 < 2; ++k01) {
            short8 af[MI], bfr[4];
            #pragma unroll
            for (int x = 0; x < MI; ++x)
                af[x] = ldsw(Asm_, wm * (MI * 16) + (x << 4) + (lane & 15),
                             (k01 << 2) + (lane >> 4));
            #pragma unroll
            for (int x = 0; x < 4; ++x)
                bfr[x] = ldsw(Bsm, (wn << 6) + (x << 4) + (lane & 15),
                              (k01 << 2) + (lane >> 4));
            __builtin_amdgcn_s_setprio(1);
            #pragma unroll
            for (int mi = 0; mi < MI; ++mi)
                #pragma unroll
                for (int ni = 0; ni < 4; ++ni)
                    acc[mi][ni] = __builtin_amdgcn_mfma_f32_16x16x32_bf16(
                        af[mi], bfr[ni], acc[mi][ni], 0, 0, 0);
            __builtin_amdgcn_s_setprio(0);
        }
    }

    // epilogue
    const int nb = n0 + (wn << 6) + (lane & 15);
    const int mb = m0 + wm * (MI * 16) + ((lane >> 4) << 2);
    float bsv[4];
    #pragma unroll
    for (int ni = 0; ni < 4; ++ni) bsv[ni] = bias[nb + (ni << 4)];
    const int sec = n0 >> 9;   // 0:q 1:k 2:v (uniform per block)

    #pragma unroll
    for (int mi = 0; mi < MI; ++mi) {
        #pragma unroll
        for (int r = 0; r < 4; ++r) {
            const int m = mb + (mi << 4) + r;
            float scale = 1.f;
            if (MODE == 0) {
                // q-scale includes log2(e) so softmax can use raw 2^x
                if (sec == 0)      scale = 0.18033688f * __expf(tptr[m] * 1e-6f);
                else if (sec == 1) scale = __expf(tptr[m] * -1e-6f);
            }
            #pragma unroll
            for (int ni = 0; ni < 4; ++ni) {
                const int n = nb + (ni << 4);
                const float v = acc[mi][ni][r] + bsv[ni];
                if (MODE == 0) {
                    const int l_seq = m >> 3, bb2 = m & 7;
                    const int hh = (n & 511) >> 6, dd = n & 63;
                    u16* dst = (sec == 0) ? qh : (sec == 1) ? kh : vh;
                    dst[(((size_t)(bb2 << 3) + hh) * L_SEQ + l_seq) * D_H + dd] = f2bf(v * scale);
                } else {
                    outf[(size_t)m * 512 + n] = v;
                }
            }
        }
    }
}

// ---------------------------------------------------------------------------
// V transpose: vh [bh][kv][d] bf16 -> vt [bh][d][kv] bf16 (64x64 tiles via LDS)
// ---------------------------------------------------------------------------
__global__ __launch_bounds__(256) void transpose_v(
    const u16* __restrict__ vh, u16* __restrict__ vt)
{
    __shared__ __align__(16) u16 T[64 * 64];
    const int bh = blockIdx.x, kt = blockIdx.y;
    const u16* src = vh + ((size_t)bh * L_SEQ + kt * 64) * D_H;

    #pragma unroll
    for (int rnd = 0; rnd < 2; ++rnd) {
        const int slot = rnd * 256 + threadIdx.x;   // 0..511
        const int row = slot >> 3, c = slot & 7;    // row = kv, c = 16B d-chunk
        const uint4 v = *reinterpret_cast<const uint4*>(src + row * 64 + c * 8);
        const int cs = c ^ (row & 7) ^ ((row >> 3) & 7);
        *reinterpret_cast<uint4*>(&T[row * 64 + cs * 8]) = v;
    }
    __syncthreads();
    #pragma unroll
    for (int rnd = 0; rnd < 2; ++rnd) {
        const int slot = rnd * 256 + threadIdx.x;
        const int d = slot >> 3, kc = slot & 7;
        u16 tmp[8];
        #pragma unroll
        for (int j = 0; j < 8; ++j) {
            const int row = kc * 8 + j;
            const int col = (((d >> 3) ^ (row & 7) ^ ((row >> 3) & 7)) << 3) + (d & 7);
            tmp[j] = T[row * 64 + col];
        }
        *reinterpret_cast<uint4*>(vt + ((size_t)bh * D_H + d) * L_SEQ + kt * 64 + kc * 8) =
            *reinterpret_cast<uint4*>(tmp);
    }
}

// ---------------------------------------------------------------------------
// Flash attention, bf16 MFMA 32x32x16, swapped QK^T, exp2-domain softmax,
// defer-max, cvt_pk repack, double-buffered K/V staging (1 barrier per kt).
// 2 waves x 32 q-rows = 64 q/block; grid 64 bh x 16 qt = 1024 blocks.
// ---------------------------------------------------------------------------
__global__ __launch_bounds__(128) void attn_kernel(
    const u16* __restrict__ qh, const u16* __restrict__ kh,
    const u16* __restrict__ vt, u16* __restrict__ ao)
{
    __shared__ __align__(16) u16 SM[16384];   // 32 KB: K0|K1|V0|V1, 8 KB each

    const int tid = threadIdx.x;
    const int lane = tid & 63, w = tid >> 6;          // w in {0,1}
    const int hi = lane >> 5, q31 = lane & 31;
    const int bh = blockIdx.x, qt = blockIdx.y;
    const int b = bh >> 3, h = bh & 7;

    // Q fragments (B-operand of S^T = K @ Q^T): lane: q=q31, d = 16ks+8hi+j
    const u16* qrow = qh + ((size_t)bh * L_SEQ + qt * 64 + w * 32 + q31) * D_H;
    short8 qf[4];
    #pragma unroll
    for (int ks = 0; ks < 4; ++ks)
        qf[ks] = *reinterpret_cast<const short8*>(qrow + ks * 16 + hi * 8);

    f32x16 oacc[2];
    #pragma unroll
    for (int d = 0; d < 2; ++d)
        #pragma unroll
        for (int r = 0; r < 16; ++r) oacc[d][r] = 0.f;
    float m_run = -1e30f, l_run = 0.f;

    const u16* kbase = kh + (size_t)bh * L_SEQ * D_H;
    const u16* vbase = vt + (size_t)bh * D_H * L_SEQ;
    const int r8 = lane >> 3;
    const int csrc = ((lane & 7) ^ r8) << 3;

    // stage K/V chunk kt into buffer buf (per-wave half: 32 rows x 128 B)
    auto stage = [&](int buf, int kt) {
        #pragma unroll
        for (int i = 0; i < 4; ++i) {
            const int row = (w << 5) + (i << 3) + r8;
            gload16(kbase + (size_t)(kt * 64 + row) * 64 + csrc,
                    (char*)SM + buf * 8192 + (w << 12) + (i << 10));
            gload16(vbase + (size_t)row * 1024 + kt * 64 + csrc,
                    (char*)SM + 16384 + buf * 8192 + (w << 12) + (i << 10));
        }
    };

    int cur = 0;
    stage(0, 0);
    __syncthreads();

    for (int kt = 0; kt < 16; ++kt) {
        if (kt < 15) stage(cur ^ 1, kt + 1);     // prefetch overlaps compute below
        const u16* Kc = SM + cur * 4096;
        const u16* Vc = SM + 8192 + cur * 4096;

        // S^T[kv][q] in 2 kv-blocks of 32
        f32x16 s[2];
        #pragma unroll
        for (int d = 0; d < 2; ++d)
            #pragma unroll
            for (int r = 0; r < 16; ++r) s[d][r] = 0.f;
        __builtin_amdgcn_s_setprio(1);
        #pragma unroll
        for (int ks = 0; ks < 4; ++ks) {
            const int c = 2 * ks + hi;
            const short8 ka0 = ldsw(Kc, q31, c);
            const short8 ka1 = ldsw(Kc, 32 + q31, c);
            s[0] = __builtin_amdgcn_mfma_f32_32x32x16_bf16(ka0, qf[ks], s[0], 0, 0, 0);
            s[1] = __builtin_amdgcn_mfma_f32_32x32x16_bf16(ka1, qf[ks], s[1], 0, 0, 0);
        }
        __builtin_amdgcn_s_setprio(0);

        // online softmax, log2 domain (log2e folded into q upstream)
        float pmax = -1e30f;
        #pragma unroll
        for (int hh = 0; hh < 2; ++hh)
            #pragma unroll
            for (int r = 0; r < 16; ++r) pmax = fmaxf(pmax, s[hh][r]);
        pmax = fmaxf(pmax, __shfl_xor(pmax, 32));
        if (!__all(pmax - m_run <= 8.0f)) {      // defer-max: P bounded by 2^8
            const float mn = fmaxf(m_run, pmax);
            const float fr = EXP2(m_run - mn);
            l_run *= fr;
            oacc[0] *= fr; oacc[1] *= fr;
            m_run = mn;
        }
        float p[2][16];
        float sum = 0.f;
        #pragma unroll
        for (int hh = 0; hh < 2; ++hh)
            #pragma unroll
            for (int r = 0; r < 16; ++r) {
                const float e = EXP2(s[hh][r] - m_run);
                p[hh][r] = e; sum += e;
            }
        sum += __shfl_xor(sum, 32);
        l_run += sum;

        // P -> bf16 b_frags (cvt_pk + lane^32 exchange) + PV MFMAs
        __builtin_amdgcn_s_setprio(1);
        #pragma unroll
        for (int ks = 0; ks < 4; ++ks) {
            const int e = ks & 1, hh = ks >> 1;
            const u32 pkA = cvtpk(p[hh][8 * e + 0], p[hh][8 * e + 1]);
            const u32 pkB = cvtpk(p[hh][8 * e + 2], p[hh][8 * e + 3]);
            const u32 pkC = cvtpk(p[hh][8 * e + 4], p[hh][8 * e + 5]);
            const u32 pkD = cvtpk(p[hh][8 * e + 6], p[hh][8 * e + 7]);
            const u32 keep0 = hi ? pkC : pkA, keep1 = hi ? pkD : pkB;
            const u32 send0 = hi ? pkA : pkC, send1 = hi ? pkB : pkD;
            const u32 r0 = (u32)__shfl_xor((int)send0, 32);
            const u32 r1 = (u32)__shfl_xor((int)send1, 32);
            union { u32 u[4]; short8 v; } pf;
            pf.u[0] = hi ? r0 : keep0;  pf.u[1] = hi ? r1 : keep1;
            pf.u[2] = hi ? keep0 : r0;  pf.u[3] = hi ? keep1 : r1;
            const int c = 2 * ks + hi;
            const short8 va0 = ldsw(Vc, q31, c);       // V^T rows = d
            const short8 va1 = ldsw(Vc, 32 + q31, c);
            oacc[0] = __builtin_amdgcn_mfma_f32_32x32x16_bf16(va0, pf.v, oacc[0], 0, 0, 0);
            oacc[1] = __builtin_amdgcn_mfma_f32_32x32x16_bf16(va1, pf.v, oacc[1], 0, 0, 0);
        }
        __builtin_amdgcn_s_setprio(0);
        __syncthreads();   // drains vmcnt(0) (prefetch done) + LDS reads complete
        cur ^= 1;
    }

    // epilogue: O^T regs -> LDS -> coalesced bf16 store (L,N,E layout)
    const float inv = 1.f / l_run;
    float* myO = (float*)SM + w * 2080;        // [32 q][65 d-padded], wave-local
    #pragma unroll
    for (int dh = 0; dh < 2; ++dh)
        #pragma unroll
        for (int r = 0; r < 16; ++r) {
            const int d = dh * 32 + (r & 3) + 8 * (r >> 2) + 4 * hi;
            myO[q31 * 65 + d] = oacc[dh][r] * inv;
        }
    __syncthreads();
    #pragma unroll
    for (int i = 0; i < 4; ++i) {
        const int slot = i * 64 + lane;
        const int qq = slot >> 3, dc = slot & 7;
        u16 outv[8];
        #pragma unroll
        for (int j = 0; j < 8; ++j) outv[j] = f2bf(myO[qq * 65 + dc * 8 + j]);
        const int lrow = qt * 64 + w * 32 + qq;
        *reinterpret_cast<uint4*>(ao + ((size_t)lrow * N_B + b) * E_DIM + h * 64 + dc * 8) =
            *reinterpret_cast<uint4*>(outv);
    }
}

// ---------------------------------------------------------------------------
extern "C" void kernel_launch(void* const* d_in, const int* in_sizes, int n_in,
                              void* d_out, int out_size, void* d_ws, size_t ws_size,
                              hipStream_t stream) {
    const float* query = (const float*)d_in[0];
    const float* timep = (const float*)d_in[1];
    const float* w_in  = (const float*)d_in[2];
    const float* b_in  = (const float*)d_in[3];
    const float* w_out = (const float*)d_in[4];
    const float* b_out = (const float*)d_in[5];
    float* out = (float*)d_out;

    u16* ws = (u16*)d_ws;
    const size_t SZ = (size_t)M_ROWS * E_DIM;        // 4194304 elems
    u16* Abf  = ws;                    // query bf16       [8192][512]
    u16* Wibf = Abf + SZ;              // w_in bf16        [1536][512]
    u16* Wobf = Wibf + 1536 * 512;     // w_out bf16       [512][512]
    u16* qhb  = Wobf + 512 * 512;      // q' head-major    [64][1024][64]
    u16* khb  = qhb + SZ;              // k'
    u16* vhb  = khb + SZ;              // v
    u16* vtb  = vhb + SZ;              // v^T              [64][64][1024]
    u16* aob  = vtb + SZ;              // attn out bf16    [8192][512]

    convert_kernel<<<5120, 256, 0, stream>>>(query, w_in, w_out, Abf, Wibf, Wobf);
    gemm_kernel<0, 4><<<dim3(64, 12), 256, 0, stream>>>(
        Abf, Wibf, b_in, timep, qhb, khb, vhb, nullptr);
    transpose_v<<<dim3(64, 16), 256, 0, stream>>>(vhb, vtb);
    attn_kernel<<<dim3(64, 16), 128, 0, stream>>>(qhb, khb, vtb, aob);
    gemm_kernel<1, 2><<<dim3(128, 4), 256, 0, stream>>>(
        aob, Wobf, b_out, nullptr, nullptr, nullptr, nullptr, out);
}